// Round 1
// baseline (509.709 us; speedup 1.0000x reference)
//
#include <hip/hip_runtime.h>
#include <cstdint>

// Problem constants
#define Bn   32
#define Cn   256
#define Hn   56
#define Wn   56
#define HWn  (Hn*Wn)           // 3136
#define NPIX (Bn*HWn)          // 100352
#define WELEMS (Cn*Cn*9)       // 589824
#define EPSv 1e-5f

// padded channels-last activation plane: [b][58][58][256] i8
#define PR   58
#define PPLANE (PR*PR)         // 3364

// ws layout (bytes)
#define F_WABS  0              // float index
#define F_SUM   64             // float[256]
#define F_SQ    320            // float[256]
#define STATS_BYTES 4096
#define WPK_OFF  4096                     // int8 wpk[256][2304]
#define WPK_BYTES WELEMS                  // 589824
#define ACT_OFF  (WPK_OFF + WPK_BYTES)    // 593920 (16B aligned)
#define ACT_BYTES (Bn*PPLANE*Cn)          // 27553792

typedef int v4i __attribute__((ext_vector_type(4)));

// ---------------------------------------------------------------------------
// Repack weights to i8 [co][k] with k = tap*256 + ci, value = sign(w) in {+1,-1}.
// Also reduce sum(|clip(w,-1,1)|) into wsf[F_WABS].
// One thread per (co,tap): reads 256 strided floats, writes 256 contiguous bytes.
__global__ void pack_w_i8(const float* __restrict__ w,
                          float* __restrict__ wsf,
                          int8_t* __restrict__ wpk) {
    int u = blockIdx.x * 256 + threadIdx.x;   // 9*256 = 2304 = (co,tap) pairs
    int co = u / 9;
    int t  = u - co * 9;
    // input OIHW: idx = co*2304 + ci*9 + t ; output: wpk[co*2304 + t*256 + ci]
    const float* wp = w + (size_t)co * 2304 + t;
    uint32_t* dst = (uint32_t*)(wpk + ((size_t)co * 9 + t) * 256);
    float sabs = 0.0f;
    #pragma unroll
    for (int cw = 0; cw < 64; cw++) {
        uint32_t r = 0;
        #pragma unroll
        for (int j = 0; j < 4; j++) {
            float wv = wp[(size_t)(cw * 4 + j) * 9];
            sabs += fminf(fabsf(wv), 1.0f);
            uint32_t byte = (__float_as_uint(wv) >> 31) ? 0xFFu : 0x01u;
            r |= byte << (j * 8);
        }
        dst[cw] = r;
    }
    #pragma unroll
    for (int off = 32; off; off >>= 1) sabs += __shfl_down(sabs, off);
    __shared__ float sh[4];
    if ((threadIdx.x & 63) == 0) sh[threadIdx.x >> 6] = sabs;
    __syncthreads();
    if (threadIdx.x == 0)
        atomicAdd(&wsf[F_WABS], sh[0] + sh[1] + sh[2] + sh[3]);
}

// ---------------------------------------------------------------------------
// Pack activations to zero-padded channels-last i8: act[b][y+1][x+1][ci] = sign(x).
// Padding stays 0 (memset) => taps into padding contribute 0 exactly.
__global__ void pack_x_i8(const float* __restrict__ x,
                          int8_t* __restrict__ act) {
    int v = blockIdx.x * 256 + threadIdx.x;   // 392*256 = 100352 exactly
    int b = v / HWn;
    int p = v - b * HWn;
    int y = p / Wn;
    int xx = p - y * Wn;
    const float* xp = x + (size_t)b * Cn * HWn + p;
    uint32_t* dst = (uint32_t*)(act + ((size_t)(b * PR + (y + 1)) * PR + (xx + 1)) * 256);
    #pragma unroll
    for (int cw = 0; cw < 64; cw++) {
        uint32_t r = 0;
        #pragma unroll
        for (int j = 0; j < 4; j++) {
            uint32_t sgn = __float_as_uint(xp[(size_t)(cw * 4 + j) * HWn]) >> 31;
            r |= (sgn ? 0xFFu : 0x01u) << (j * 8);
        }
        dst[cw] = r;
    }
}

// ---------------------------------------------------------------------------
// Binary conv as implicit GEMM on the i8 matrix pipe.
//   C[co][n] = sum_k A[co][k] * B[k][n],  k = tap*256 + ci,  n = linear pixel.
// Block: 256 threads = 4 waves, wave w owns co in [w*64, w*64+64).
// Wave tile: M=64 x N=128 -> 4x8 fragments of mfma_i32_16x16x64_i8.
// Fragment layouts (16x16 family, m89-verified convention):
//   A: row = lane&15, k = (lane>>4)*16 + j   (16 contiguous bytes)
//   B: col = lane&15, k = (lane>>4)*16 + j   (16 contiguous bytes, channels-last)
//   D: col = lane&15, row = (lane>>4)*4 + reg
// Epilogue: out = mean*dot + x (shortcut), fused BN-stats reduction via shfl_xor
// over the 16 lanes sharing a channel, then one atomicAdd per (co,stat).
__global__ __launch_bounds__(256, 2) void conv_mfma(
    const int8_t* __restrict__ act, const int8_t* __restrict__ wpk,
    const float* __restrict__ x, float* __restrict__ wsf,
    float* __restrict__ out) {
    const int lane = threadIdx.x & 63;
    const int wid  = threadIdx.x >> 6;     // 0..3
    const int co_w = wid * 64;
    const int p0   = blockIdx.x * 128;     // 784 blocks * 128 = 100352
    const int l15  = lane & 15;
    const int l4   = lane >> 4;            // 0..3

    // Per-N-fragment pixel bookkeeping (one pixel per lane per fragment).
    int bofs[8];    // act byte offset at window center (y+1,x+1), incl. ci part
    int obase[8];   // f32 index base: b*(256*3136) + p  (co*3136 added later)
    #pragma unroll
    for (int ni = 0; ni < 8; ni++) {
        int n = p0 + ni * 16 + l15;
        int b = n / HWn;
        int p = n - b * HWn;
        int y = p / Wn;
        int xx = p - y * Wn;
        bofs[ni] = ((b * PR + (y + 1)) * PR + (xx + 1)) * 256 + l4 * 16;
        obase[ni] = b * (Cn * HWn) + p;
    }
    int aofs[4];
    #pragma unroll
    for (int mi = 0; mi < 4; mi++)
        aofs[mi] = (co_w + mi * 16 + l15) * 2304 + l4 * 16;

    v4i acc[4][8] = {};

    for (int t = 0; t < 9; t++) {
        const int dh = t / 3 - 1;
        const int dw = t % 3 - 1;
        const int toff = (dh * PR + dw) * 256;   // tap offset from window center
        #pragma unroll
        for (int s = 0; s < 4; s++) {
            const int koff = t * 256 + s * 64;
            v4i af[4], bf[8];
            #pragma unroll
            for (int mi = 0; mi < 4; mi++)
                af[mi] = *(const v4i*)(wpk + aofs[mi] + koff);
            #pragma unroll
            for (int ni = 0; ni < 8; ni++)
                bf[ni] = *(const v4i*)(act + bofs[ni] + toff + s * 64);
            #pragma unroll
            for (int mi = 0; mi < 4; mi++) {
                #pragma unroll
                for (int ni = 0; ni < 8; ni++)
                    acc[mi][ni] = __builtin_amdgcn_mfma_i32_16x16x64_i8(
                        af[mi], bf[ni], acc[mi][ni], 0, 0, 0);
            }
        }
    }

    const float mv = wsf[F_WABS] * (1.0f / (float)WELEMS);

    // Epilogue: scale + shortcut + store + per-channel partial stats.
    float ssum[4][4] = {}, ssq[4][4] = {};
    #pragma unroll
    for (int mi = 0; mi < 4; mi++) {
        #pragma unroll
        for (int ni = 0; ni < 8; ni++) {
            v4i a = acc[mi][ni];
            #pragma unroll
            for (int q = 0; q < 4; q++) {
                int co = co_w + mi * 16 + l4 * 4 + q;
                size_t idx = (size_t)obase[ni] + (size_t)co * HWn;
                float val = fmaf(mv, (float)a[q], x[idx]);
                out[idx] = val;
                ssum[mi][q] += val;
                ssq[mi][q]  += val * val;
            }
        }
    }
    // Reduce across the 16 lanes (l15) that share each channel, then atomics.
    #pragma unroll
    for (int mi = 0; mi < 4; mi++) {
        #pragma unroll
        for (int q = 0; q < 4; q++) {
            float s = ssum[mi][q], sq = ssq[mi][q];
            #pragma unroll
            for (int off = 1; off < 16; off <<= 1) {
                s  += __shfl_xor(s, off);
                sq += __shfl_xor(sq, off);
            }
            if (l15 == 0) {
                int co = co_w + mi * 16 + l4 * 4 + q;
                atomicAdd(&wsf[F_SUM + co], s);
                atomicAdd(&wsf[F_SQ  + co], sq);
            }
        }
    }
}

// ---------------------------------------------------------------------------
// BN finalize (per-plane, from fused stats) + normalize + ReLU, in place.
__global__ void epilogue_kernel(float* __restrict__ out,
                                const float* __restrict__ wsf,
                                const float* __restrict__ g,
                                const float* __restrict__ bt) {
    int plane = blockIdx.x;   // b*256 + c
    int c = plane & 255;
    const float n = (float)(Bn * HWn);
    float mean = wsf[F_SUM + c] / n;
    float var  = wsf[F_SQ + c] / n - mean * mean;
    float sc = g[c] * rsqrtf(var + EPSv);
    float sh = bt[c] - mean * sc;
    float4* o4 = (float4*)(out + (size_t)plane * HWn);
    for (int i = threadIdx.x; i < HWn / 4; i += 256) {
        float4 v = o4[i];
        v.x = fmaxf(fmaf(v.x, sc, sh), 0.0f);
        v.y = fmaxf(fmaf(v.y, sc, sh), 0.0f);
        v.z = fmaxf(fmaf(v.z, sc, sh), 0.0f);
        v.w = fmaxf(fmaf(v.w, sc, sh), 0.0f);
        o4[i] = v;
    }
}

// ---------------------------------------------------------------------------
extern "C" void kernel_launch(void* const* d_in, const int* in_sizes, int n_in,
                              void* d_out, int out_size, void* d_ws, size_t ws_size,
                              hipStream_t stream) {
    const float* x     = (const float*)d_in[0];
    const float* w     = (const float*)d_in[1];
    const float* gamma = (const float*)d_in[2];
    const float* beta  = (const float*)d_in[3];
    float* out = (float*)d_out;

    float*  wsf = (float*)d_ws;
    int8_t* wpk = (int8_t*)d_ws + WPK_OFF;
    int8_t* act = (int8_t*)d_ws + ACT_OFF;

    hipMemsetAsync(d_ws, 0, STATS_BYTES, stream);
    hipMemsetAsync(act, 0, ACT_BYTES, stream);
    pack_w_i8<<<dim3(9),   dim3(256), 0, stream>>>(w, wsf, wpk);
    pack_x_i8<<<dim3(392), dim3(256), 0, stream>>>(x, act);
    conv_mfma<<<dim3(784), dim3(256), 0, stream>>>(act, wpk, x, wsf, out);
    epilogue_kernel<<<dim3(Bn * Cn), dim3(256), 0, stream>>>(out, wsf, gamma, beta);
}

// Round 2
// 367.295 us; speedup vs baseline: 1.3877x; 1.3877x over previous
//
#include <hip/hip_runtime.h>
#include <cstdint>

// Problem constants
#define Bn   32
#define Cn   256
#define Hn   56
#define Wn   56
#define HWn  (Hn*Wn)           // 3136
#define NPIX (Bn*HWn)          // 100352
#define WELEMS (Cn*Cn*9)       // 589824
#define EPSv 1e-5f

// padded channels-last activation plane: [b][58 rows][58 cols][256 ci] i8
// per-pixel 256B block stored XOR-swizzled: 16B slot s lives at s ^ (padded_col & 15)
#define PR   58
#define PPLANE (PR*PR)         // 3364

// ws layout (bytes)
#define F_WABS  0              // float index
#define F_SUM   64             // float[256]
#define F_SQ    320            // float[256]
#define STATS_BYTES 4096
#define WPK_OFF  4096                     // i8 wpk[kc=36][co=256][64]  (A repack)
#define WPK_BYTES WELEMS                  // 589824
#define ACT_OFF  (WPK_OFF + WPK_BYTES)    // 593920 (16B aligned)
#define ACT_BYTES (Bn*PPLANE*Cn)          // 27553792

typedef int v4i __attribute__((ext_vector_type(4)));

// ---------------------------------------------------------------------------
// Repack weights to A-GEMM layout: wpk[(kc*256 + co)*64 + cb], kc = t*4+s,
// cb = ci - s*64, value = sign(w) in {+1,-1} as i8. Every A-fragment load in
// conv is then one fully-contiguous 1KB wave load.
// Also reduce sum(|clip(w,-1,1)|) into wsf[F_WABS].
__global__ void pack_w_i8(const float* __restrict__ w,
                          float* __restrict__ wsf,
                          uint8_t* __restrict__ wpk) {
    int u = blockIdx.x * 256 + threadIdx.x;   // 36*256 = 9216 = co*36 + kc
    int co = u / 36;
    int kc = u - co * 36;
    int t  = kc >> 2;          // tap
    int s  = kc & 3;           // 64-ci chunk
    // input OIHW: w[co*2304 + ci*9 + t]
    const float* wp = w + (size_t)co * 2304 + t;
    uint32_t* dst = (uint32_t*)(wpk + ((size_t)kc * 256 + co) * 64);
    float sabs = 0.0f;
    #pragma unroll
    for (int cw = 0; cw < 16; cw++) {
        uint32_t r = 0;
        #pragma unroll
        for (int j = 0; j < 4; j++) {
            int ci = s * 64 + cw * 4 + j;
            float wv = wp[(size_t)ci * 9];
            sabs += fminf(fabsf(wv), 1.0f);
            r |= ((__float_as_uint(wv) >> 31) ? 0xFFu : 0x01u) << (j * 8);
        }
        dst[cw] = r;
    }
    #pragma unroll
    for (int off = 32; off; off >>= 1) sabs += __shfl_down(sabs, off);
    __shared__ float sh[4];
    if ((threadIdx.x & 63) == 0) sh[threadIdx.x >> 6] = sabs;
    __syncthreads();
    if (threadIdx.x == 0)
        atomicAdd(&wsf[F_WABS], sh[0] + sh[1] + sh[2] + sh[3]);
}

// ---------------------------------------------------------------------------
// Pack activations to zero-padded channels-last i8 with per-pixel XOR swizzle:
// 16B slot `slot` of pixel at padded col pc is stored at slot ^ (pc & 15).
// Padding stays 0 (memset); zeros are swizzle-invariant.
__global__ void pack_x_i8(const float* __restrict__ x,
                          uint8_t* __restrict__ act) {
    int v = blockIdx.x * 256 + threadIdx.x;   // 392*256 = 100352 exactly
    int b = v / HWn;
    int p = v - b * HWn;
    int y = p / Wn;
    int xx = p - y * Wn;
    const float* xp = x + (size_t)b * Cn * HWn + p;
    int key = (xx + 1) & 15;
    uint32_t* dst = (uint32_t*)(act + ((size_t)(b * PR + (y + 1)) * PR + (xx + 1)) * 256);
    #pragma unroll
    for (int slot = 0; slot < 16; slot++) {
        uint32_t rr[4];
        #pragma unroll
        for (int cw = 0; cw < 4; cw++) {
            uint32_t r = 0;
            #pragma unroll
            for (int j = 0; j < 4; j++) {
                uint32_t sgn = __float_as_uint(xp[(size_t)(slot * 16 + cw * 4 + j) * HWn]) >> 31;
                r |= (sgn ? 0xFFu : 0x01u) << (j * 8);
            }
            rr[cw] = r;
        }
        *(uint4*)(dst + (size_t)((slot ^ key) * 4)) = make_uint4(rr[0], rr[1], rr[2], rr[3]);
    }
}

// ---------------------------------------------------------------------------
// Binary conv as implicit GEMM on the i8 matrix pipe, LDS-staged B.
// Block = (batch b, output row-pair y0..y0+1): N-tile = 112 pixels, M = 256.
// 4 waves, wave w owns co in [w*64, w*64+64): 4 M-frags x 7 N-frags of
// mfma_i32_16x16x64_i8, K-loop = 9 taps x 4 chunks of 64 ci.
// B staged ONCE into LDS (4 padded rows x 58 x 256B = 59392B), reused by all
// taps. ds_reads hit <=2-way banks thanks to the baked-in XOR swizzle.
// A streamed from global, each fragment load = contiguous 1KB (L2-resident).
// Epilogue: out = mean*dot + x, fused BN-stats via shfl_xor + atomics.
__global__ __launch_bounds__(256, 2) void conv_mfma(
    const uint8_t* __restrict__ act, const uint8_t* __restrict__ wpk,
    const float* __restrict__ x, float* __restrict__ wsf,
    float* __restrict__ out) {
    __shared__ uint4 ldsv[3712];              // 59392 B
    uint8_t* lds = (uint8_t*)ldsv;

    const int tid  = threadIdx.x;
    const int lane = tid & 63;
    const int wid  = tid >> 6;                // 0..3
    const int l15  = lane & 15;
    const int l4   = lane >> 4;               // 0..3

    const int bx = blockIdx.x;                // 0..895
    const int b  = bx / 28;
    const int y0 = (bx - b * 28) * 2;         // first output image row

    // Stage padded rows y0..y0+3 = one contiguous 59392B block of act.
    {
        const uint4* src = (const uint4*)(act + ((size_t)b * PR + y0) * PR * 256);
        for (int i = tid; i < 3712; i += 256) ldsv[i] = src[i];
    }
    __syncthreads();

    // Per-N-fragment pixel bookkeeping (pixel n = ni*16 + l15, n in [0,112)).
    int rr1[7], cc1[7], obn[7];
    #pragma unroll
    for (int ni = 0; ni < 7; ni++) {
        int n  = ni * 16 + l15;
        int r_ = n / 56;
        int c_ = n - r_ * 56;
        rr1[ni] = r_ + 1;      // staged-local row of center (stage holds rows -1..+2)
        cc1[ni] = c_ + 1;      // padded col of center
        obn[ni] = n;
    }
    // A-fragment lane offset (co = wid*64 + mi*16 + l15, bytes l4*16)
    const int aoffb = (wid * 64 + l15) * 64 + l4 * 16;

    v4i acc[4][7] = {};

    for (int t = 0; t < 9; t++) {
        const int dh = t / 3 - 1;
        const int dw = t % 3 - 1;
        int pixb[7], key[7];
        #pragma unroll
        for (int ni = 0; ni < 7; ni++) {
            int lc = cc1[ni] + dw;
            pixb[ni] = ((rr1[ni] + dh) * 58 + lc) * 256;
            key[ni]  = lc & 15;
        }
        #pragma unroll
        for (int s = 0; s < 4; s++) {
            const int kc = t * 4 + s;
            v4i af[4];
            #pragma unroll
            for (int mi = 0; mi < 4; mi++)
                af[mi] = *(const v4i*)(wpk + (size_t)kc * 16384 + mi * 1024 + aoffb);
            v4i bf[7];
            #pragma unroll
            for (int ni = 0; ni < 7; ni++)
                bf[ni] = *(const v4i*)(lds + pixb[ni] + (((s * 4 + l4) ^ key[ni]) << 4));
            #pragma unroll
            for (int mi = 0; mi < 4; mi++) {
                #pragma unroll
                for (int ni = 0; ni < 7; ni++)
                    acc[mi][ni] = __builtin_amdgcn_mfma_i32_16x16x64_i8(
                        af[mi], bf[ni], acc[mi][ni], 0, 0, 0);
            }
        }
    }

    const float mv = wsf[F_WABS] * (1.0f / (float)WELEMS);
    const int co_w = wid * 64;
    const int pbase = b * (Cn * HWn) + y0 * 56;

    // Epilogue: scale + shortcut + store + per-channel partial stats.
    float ssum[4][4] = {}, ssq[4][4] = {};
    #pragma unroll
    for (int mi = 0; mi < 4; mi++) {
        #pragma unroll
        for (int ni = 0; ni < 7; ni++) {
            v4i a = acc[mi][ni];
            #pragma unroll
            for (int q = 0; q < 4; q++) {
                int co = co_w + mi * 16 + l4 * 4 + q;
                size_t idx = (size_t)pbase + (size_t)co * HWn + obn[ni];
                float val = fmaf(mv, (float)a[q], x[idx]);
                out[idx] = val;
                ssum[mi][q] += val;
                ssq[mi][q]  += val * val;
            }
        }
    }
    // Reduce across the 16 lanes (l15) sharing each channel, then atomics.
    #pragma unroll
    for (int mi = 0; mi < 4; mi++) {
        #pragma unroll
        for (int q = 0; q < 4; q++) {
            float s = ssum[mi][q], sq = ssq[mi][q];
            #pragma unroll
            for (int off = 1; off < 16; off <<= 1) {
                s  += __shfl_xor(s, off);
                sq += __shfl_xor(sq, off);
            }
            if (l15 == 0) {
                int co = co_w + mi * 16 + l4 * 4 + q;
                atomicAdd(&wsf[F_SUM + co], s);
                atomicAdd(&wsf[F_SQ  + co], sq);
            }
        }
    }
}

// ---------------------------------------------------------------------------
// BN finalize (per-plane, from fused stats) + normalize + ReLU, in place.
__global__ void epilogue_kernel(float* __restrict__ out,
                                const float* __restrict__ wsf,
                                const float* __restrict__ g,
                                const float* __restrict__ bt) {
    int plane = blockIdx.x;   // b*256 + c
    int c = plane & 255;
    const float n = (float)(Bn * HWn);
    float mean = wsf[F_SUM + c] / n;
    float var  = wsf[F_SQ + c] / n - mean * mean;
    float sc = g[c] * rsqrtf(var + EPSv);
    float sh = bt[c] - mean * sc;
    float4* o4 = (float4*)(out + (size_t)plane * HWn);
    for (int i = threadIdx.x; i < HWn / 4; i += 256) {
        float4 v = o4[i];
        v.x = fmaxf(fmaf(v.x, sc, sh), 0.0f);
        v.y = fmaxf(fmaf(v.y, sc, sh), 0.0f);
        v.z = fmaxf(fmaf(v.z, sc, sh), 0.0f);
        v.w = fmaxf(fmaf(v.w, sc, sh), 0.0f);
        o4[i] = v;
    }
}

// ---------------------------------------------------------------------------
extern "C" void kernel_launch(void* const* d_in, const int* in_sizes, int n_in,
                              void* d_out, int out_size, void* d_ws, size_t ws_size,
                              hipStream_t stream) {
    const float* x     = (const float*)d_in[0];
    const float* w     = (const float*)d_in[1];
    const float* gamma = (const float*)d_in[2];
    const float* beta  = (const float*)d_in[3];
    float* out = (float*)d_out;

    float*   wsf = (float*)d_ws;
    uint8_t* wpk = (uint8_t*)d_ws + WPK_OFF;
    uint8_t* act = (uint8_t*)d_ws + ACT_OFF;

    hipMemsetAsync(d_ws, 0, STATS_BYTES, stream);
    hipMemsetAsync(act, 0, ACT_BYTES, stream);
    pack_w_i8<<<dim3(36),  dim3(256), 0, stream>>>(w, wsf, wpk);
    pack_x_i8<<<dim3(392), dim3(256), 0, stream>>>(x, act);
    conv_mfma<<<dim3(896), dim3(256), 0, stream>>>(act, wpk, x, wsf, out);
    epilogue_kernel<<<dim3(Bn * Cn), dim3(256), 0, stream>>>(out, wsf, gamma, beta);
}